// Round 4
// baseline (164.786 us; speedup 1.0000x reference)
//
#include <hip/hip_runtime.h>
#include <hip/hip_bf16.h>

#define N_EDGES_C 600000
#define D_C 128

typedef __attribute__((ext_vector_type(8))) short short8;
typedef __attribute__((ext_vector_type(4))) float f32x4;

__device__ inline unsigned short f2bf(float f) {
    unsigned int u = __builtin_bit_cast(unsigned int, f);
    u += 0x7FFF + ((u >> 16) & 1);          // round-nearest-even
    return (unsigned short)(u >> 16);
}

__device__ inline unsigned int pk2bf(float lo, float hi) {
    return (unsigned int)f2bf(lo) | ((unsigned int)f2bf(hi) << 16);
}

// Fragment-ordered W1 (bf16): w1f[((nf*8+kk)*64 + lane)*8 + j] =
//   W1[(kk*32 + (lane>>4)*8 + j) * 256 + nf*16 + (lane&15)]
// so each (nf,kk) B-fragment is one contiguous, coalesced 1KB wave load.
__global__ void prep_w1f(const float* __restrict__ W1, unsigned short* __restrict__ w1f) {
    int o = blockIdx.x * 256 + threadIdx.x;   // 0..65535
    int j    = o & 7;
    int lane = (o >> 3) & 63;
    int kk   = (o >> 9) & 7;
    int nf   = o >> 12;
    int k = kk * 32 + (lane >> 4) * 8 + j;
    int n = nf * 16 + (lane & 15);
    w1f[o] = f2bf(W1[k * 256 + n]);
}

__global__ __launch_bounds__(256) void edge_mlp(
    const float* __restrict__ emd,
    const int* __restrict__ eidx,
    const unsigned short* __restrict__ w1f,
    const float* __restrict__ b1,
    const float* __restrict__ W2,
    const float* __restrict__ b2,
    float* __restrict__ out)
{
    // A-tile stored in MFMA *fragment order*:
    //   element (row = m*16+rr, k = kk*32 + kl*8 + j) at
    //   smem[(m*8+kk)*1024 + (kl*16+rr)*16 + j*2]
    // -> MFMA a-read = contiguous 1KB per wave (conflict-free);
    //    staging write = each wave covers one 512B region exactly once per iter.
    __shared__ unsigned char smem[32768];

    const int t    = threadIdx.x;
    const int lane = t & 63;
    const int wv   = t >> 6;      // wave id: stages m-slab wv; computes n-cols wv*64..+63
    const int rr   = lane & 15;
    const int lg   = lane >> 4;   // 0..3

    const int e0 = blockIdx.x * 64;

    // ---- stage: wave wv stages rows wv*16 .. wv*16+15 (its m-slab) ----
    {
        const int row = wv * 16 + rr;
        const int2 e2 = *reinterpret_cast<const int2*>(eidx + (size_t)(e0 + row) * 2);
        const float* ps = emd + (size_t)e2.x * D_C + lg * 4;
        const float* pd = emd + (size_t)e2.y * D_C + lg * 4;
        unsigned char* sw = smem + (wv * 8192 + (lg >> 1) * 256 + rr * 16 + (lg & 1) * 8);

        #pragma unroll
        for (int it = 0; it < 16; ++it) {
            const float* p = (it < 8) ? ps : pd;          // compile-time (unrolled)
            const float4 v = *reinterpret_cast<const float4*>(p + (it & 7) * 16);
            uint2 pk;
            pk.x = pk2bf(v.x, v.y);
            pk.y = pk2bf(v.z, v.w);
            *reinterpret_cast<uint2*>(sw + it * 512) = pk;
        }
    }
    __syncthreads();

    // ---- MFMA: each wave computes all 64 rows x its 64 output cols ----
    f32x4 acc[4][4];              // [m-frag][n-frag]
    #pragma unroll
    for (int m = 0; m < 4; ++m)
        #pragma unroll
        for (int n4 = 0; n4 < 4; ++n4) acc[m][n4] = (f32x4){0.f, 0.f, 0.f, 0.f};

    #pragma unroll
    for (int kk = 0; kk < 8; ++kk) {
        short8 a[4];
        #pragma unroll
        for (int m = 0; m < 4; ++m)
            a[m] = *reinterpret_cast<const short8*>(smem + (m * 8 + kk) * 1024 + lane * 16);
        #pragma unroll
        for (int n4 = 0; n4 < 4; ++n4) {
            short8 b = *reinterpret_cast<const short8*>(
                w1f + ((size_t)((wv * 4 + n4) * 8 + kk) * 64 + lane) * 8);
            #pragma unroll
            for (int m = 0; m < 4; ++m)
                acc[m][n4] = __builtin_amdgcn_mfma_f32_16x16x32_bf16(a[m], b, acc[m][n4], 0, 0, 0);
        }
    }

    // ---- fused epilogue: relu(acc + b1) * W2 -> per-lane partial logits ----
    float pr[4][4];
    #pragma unroll
    for (int m = 0; m < 4; ++m)
        #pragma unroll
        for (int g = 0; g < 4; ++g) pr[m][g] = 0.f;

    #pragma unroll
    for (int n4 = 0; n4 < 4; ++n4) {
        int n = wv * 64 + n4 * 16 + rr;      // C/D col = lane&15
        float b1v = b1[n];
        float w2v = W2[n];
        #pragma unroll
        for (int m = 0; m < 4; ++m)
            #pragma unroll
            for (int g = 0; g < 4; ++g) {
                float h = acc[m][n4][g] + b1v;
                h = h > 0.f ? h : 0.f;
                pr[m][g] += h * w2v;
            }
    }

    // reduce over the 16 cols held across rr lanes
    #pragma unroll
    for (int msk = 8; msk >= 1; msk >>= 1) {
        #pragma unroll
        for (int m = 0; m < 4; ++m)
            #pragma unroll
            for (int g = 0; g < 4; ++g)
                pr[m][g] += __shfl_xor(pr[m][g], msk, 64);
    }

    __syncthreads();                 // A-tile reads done; safe to reuse smem
    float* partial = (float*)smem;   // [4 waves][64 rows]

    if (rr == 0) {
        #pragma unroll
        for (int m = 0; m < 4; ++m)
            #pragma unroll
            for (int g = 0; g < 4; ++g)
                partial[wv * 64 + m * 16 + lg * 4 + g] = pr[m][g];
    }
    __syncthreads();

    // final cross-wave sum + sigmoid
    if (t < 64) {
        float s = partial[t] + partial[64 + t] + partial[128 + t] + partial[192 + t] + b2[0];
        out[e0 + t] = 1.0f / (1.0f + __expf(-s));
    }
}

extern "C" void kernel_launch(void* const* d_in, const int* in_sizes, int n_in,
                              void* d_out, int out_size, void* d_ws, size_t ws_size,
                              hipStream_t stream) {
    const float* emd  = (const float*)d_in[0];
    const int*   eidx = (const int*)d_in[1];
    const float* W1   = (const float*)d_in[2];
    const float* b1   = (const float*)d_in[3];
    const float* W2   = (const float*)d_in[4];
    const float* b2   = (const float*)d_in[5];
    float* out = (float*)d_out;
    unsigned short* w1f = (unsigned short*)d_ws;   // 256*256 bf16 = 128KB, fragment-ordered

    prep_w1f<<<256, 256, 0, stream>>>(W1, w1f);

    const int nblocks = N_EDGES_C / 64;            // 9375, exact
    edge_mlp<<<nblocks, 256, 0, stream>>>(emd, eidx, w1f, b1, W2, b2, out);
}

// Round 5
// 162.475 us; speedup vs baseline: 1.0142x; 1.0142x over previous
//
#include <hip/hip_runtime.h>
#include <hip/hip_bf16.h>

#define N_EDGES_C 600000
#define D_C 128

typedef __attribute__((ext_vector_type(8))) short short8;
typedef __attribute__((ext_vector_type(4))) float f32x4;

__device__ inline unsigned short f2bf(float f) {
    unsigned int u = __builtin_bit_cast(unsigned int, f);
    u += 0x7FFF + ((u >> 16) & 1);          // round-nearest-even
    return (unsigned short)(u >> 16);
}

__device__ inline unsigned int pk2bf(float lo, float hi) {
    return (unsigned int)f2bf(lo) | ((unsigned int)f2bf(hi) << 16);
}

// Fragment-ordered W1 (bf16): w1f[((nf*8+kk)*64 + lane)*8 + j] =
//   W1[(kk*32 + (lane>>4)*8 + j) * 256 + nf*16 + (lane&15)]
// so each (nf,kk) B-fragment is one contiguous, coalesced 1KB wave load.
__global__ void prep_w1f(const float* __restrict__ W1, unsigned short* __restrict__ w1f) {
    int o = blockIdx.x * 256 + threadIdx.x;   // 0..65535
    int j    = o & 7;
    int lane = (o >> 3) & 63;
    int kk   = (o >> 9) & 7;
    int nf   = o >> 12;
    int k = kk * 32 + (lane >> 4) * 8 + j;
    int n = nf * 16 + (lane & 15);
    w1f[o] = f2bf(W1[k * 256 + n]);
}

__global__ __launch_bounds__(256, 4) void edge_mlp(
    const float* __restrict__ emd,
    const int* __restrict__ eidx,
    const unsigned short* __restrict__ w1f,
    const float* __restrict__ b1,
    const float* __restrict__ W2,
    const float* __restrict__ b2,
    float* __restrict__ out)
{
    // A-tile stored in MFMA *fragment order*:
    //   element (row = m*16+rr, k = kk*32 + kl*8 + j) at
    //   smem[(m*8+kk)*1024 + (kl*16+rr)*16 + j*2]
    // -> MFMA a-read = contiguous 1KB per wave (conflict-free);
    //    staging write = each wave covers one 512B region exactly once per iter.
    __shared__ unsigned char smem[32768];

    const int t    = threadIdx.x;
    const int lane = t & 63;
    const int wv   = t >> 6;      // wave id: stages m-slab wv; computes n-cols wv*64..+63
    const int rr   = lane & 15;
    const int lg   = lane >> 4;   // 0..3

    const int e0 = blockIdx.x * 64;

    // ---- stage: wave wv stages rows wv*16 .. wv*16+15 (its m-slab) ----
    {
        const int row = wv * 16 + rr;
        const int2 e2 = *reinterpret_cast<const int2*>(eidx + (size_t)(e0 + row) * 2);
        const float* ps = emd + (size_t)e2.x * D_C + lg * 4;
        const float* pd = emd + (size_t)e2.y * D_C + lg * 4;
        unsigned char* sw = smem + (wv * 8192 + (lg >> 1) * 256 + rr * 16 + (lg & 1) * 8);

        #pragma unroll
        for (int it = 0; it < 16; ++it) {
            const float* p = (it < 8) ? ps : pd;          // compile-time (unrolled)
            const float4 v = *reinterpret_cast<const float4*>(p + (it & 7) * 16);
            uint2 pk;
            pk.x = pk2bf(v.x, v.y);
            pk.y = pk2bf(v.z, v.w);
            *reinterpret_cast<uint2*>(sw + it * 512) = pk;
        }
    }
    __syncthreads();

    // ---- MFMA: each wave computes all 64 rows x its 64 output cols ----
    f32x4 acc[4][4];              // [m-frag][n-frag]
    #pragma unroll
    for (int m = 0; m < 4; ++m)
        #pragma unroll
        for (int n4 = 0; n4 < 4; ++n4) acc[m][n4] = (f32x4){0.f, 0.f, 0.f, 0.f};

    #pragma unroll
    for (int kk = 0; kk < 8; ++kk) {
        short8 a[4];
        #pragma unroll
        for (int m = 0; m < 4; ++m)
            a[m] = *reinterpret_cast<const short8*>(smem + (m * 8 + kk) * 1024 + lane * 16);
        #pragma unroll
        for (int n4 = 0; n4 < 4; ++n4) {
            short8 b = *reinterpret_cast<const short8*>(
                w1f + ((size_t)((wv * 4 + n4) * 8 + kk) * 64 + lane) * 8);
            #pragma unroll
            for (int m = 0; m < 4; ++m)
                acc[m][n4] = __builtin_amdgcn_mfma_f32_16x16x32_bf16(a[m], b, acc[m][n4], 0, 0, 0);
        }
    }

    // ---- fused epilogue: relu(acc + b1) * W2 -> per-lane partial logits ----
    float pr[4][4];
    #pragma unroll
    for (int m = 0; m < 4; ++m)
        #pragma unroll
        for (int g = 0; g < 4; ++g) pr[m][g] = 0.f;

    #pragma unroll
    for (int n4 = 0; n4 < 4; ++n4) {
        int n = wv * 64 + n4 * 16 + rr;      // C/D col = lane&15
        float b1v = b1[n];
        float w2v = W2[n];
        #pragma unroll
        for (int m = 0; m < 4; ++m)
            #pragma unroll
            for (int g = 0; g < 4; ++g) {
                float h = acc[m][n4][g] + b1v;
                h = h > 0.f ? h : 0.f;
                pr[m][g] += h * w2v;
            }
    }

    // reduce over the 16 cols held across rr lanes
    #pragma unroll
    for (int msk = 8; msk >= 1; msk >>= 1) {
        #pragma unroll
        for (int m = 0; m < 4; ++m)
            #pragma unroll
            for (int g = 0; g < 4; ++g)
                pr[m][g] += __shfl_xor(pr[m][g], msk, 64);
    }

    __syncthreads();                 // A-tile reads done; safe to reuse smem
    float* partial = (float*)smem;   // [4 waves][64 rows]

    if (rr == 0) {
        #pragma unroll
        for (int m = 0; m < 4; ++m)
            #pragma unroll
            for (int g = 0; g < 4; ++g)
                partial[wv * 64 + m * 16 + lg * 4 + g] = pr[m][g];
    }
    __syncthreads();

    // final cross-wave sum + sigmoid
    if (t < 64) {
        float s = partial[t] + partial[64 + t] + partial[128 + t] + partial[192 + t] + b2[0];
        out[e0 + t] = 1.0f / (1.0f + __expf(-s));
    }
}

extern "C" void kernel_launch(void* const* d_in, const int* in_sizes, int n_in,
                              void* d_out, int out_size, void* d_ws, size_t ws_size,
                              hipStream_t stream) {
    const float* emd  = (const float*)d_in[0];
    const int*   eidx = (const int*)d_in[1];
    const float* W1   = (const float*)d_in[2];
    const float* b1   = (const float*)d_in[3];
    const float* W2   = (const float*)d_in[4];
    const float* b2   = (const float*)d_in[5];
    float* out = (float*)d_out;
    unsigned short* w1f = (unsigned short*)d_ws;   // 256*256 bf16 = 128KB, fragment-ordered

    prep_w1f<<<256, 256, 0, stream>>>(W1, w1f);

    const int nblocks = N_EDGES_C / 64;            // 9375, exact
    edge_mlp<<<nblocks, 256, 0, stream>>>(emd, eidx, w1f, b1, W2, b2, out);
}

// Round 6
// 161.902 us; speedup vs baseline: 1.0178x; 1.0035x over previous
//
#include <hip/hip_runtime.h>
#include <hip/hip_bf16.h>

#define N_EDGES_C 600000
#define D_C 128

typedef __attribute__((ext_vector_type(8))) short short8;
typedef __attribute__((ext_vector_type(4))) float f32x4;

__device__ inline unsigned short f2bf(float f) {
    unsigned int u = __builtin_bit_cast(unsigned int, f);
    u += 0x7FFF + ((u >> 16) & 1);          // round-nearest-even
    return (unsigned short)(u >> 16);
}

__device__ inline unsigned int pk2bf(float lo, float hi) {
    return (unsigned int)f2bf(lo) | ((unsigned int)f2bf(hi) << 16);
}

// Fragment-ordered W1 (bf16): w1f[((nf*8+kk)*64 + lane)*8 + j] =
//   W1[(kk*32 + (lane>>4)*8 + j) * 256 + nf*16 + (lane&15)]
// so each (nf,kk) B-fragment is one contiguous, coalesced 1KB wave load.
__global__ void prep_w1f(const float* __restrict__ W1, unsigned short* __restrict__ w1f) {
    int o = blockIdx.x * 256 + threadIdx.x;   // 0..65535
    int j    = o & 7;
    int lane = (o >> 3) & 63;
    int kk   = (o >> 9) & 7;
    int nf   = o >> 12;
    int k = kk * 32 + (lane >> 4) * 8 + j;
    int n = nf * 16 + (lane & 15);
    w1f[o] = f2bf(W1[k * 256 + n]);
}

__global__ __launch_bounds__(256, 4) void edge_mlp(
    const float* __restrict__ emd,
    const int* __restrict__ eidx,
    const unsigned short* __restrict__ w1f,
    const float* __restrict__ b1,
    const float* __restrict__ W2,
    const float* __restrict__ b2,
    float* __restrict__ out)
{
    // A-tile in MFMA fragment order with both-sides XOR swizzle:
    //   logical element (row = m*16+rr, k = kk*32+kl*8+j)
    //   physical byte  smem[(m*8+kk)*1024 + (kl*16 + (rr^kk))*16 + j*2]
    // Staging: one full edge row (2x512B coalesced global read) per wave-instr;
    //   LDS write = 32x16B segments, colors (rr^kk)&7 -> 4 segs/color = optimal.
    // MFMA read: per (m,kk) a bijective lane->slot map over the full 1KB block
    //   -> conflict-free.
    __shared__ unsigned char smem[32768];

    const int t    = threadIdx.x;
    const int lane = t & 63;
    const int wv   = t >> 6;      // wave id: computes n-cols wv*64..+63
    const int rr_c = lane & 15;   // C/D col lane within 16
    const int lg   = lane >> 4;

    const int e0 = blockIdx.x * 64;

    // ---- stage: per p, wave wv stages row p*4+wv (one coalesced 1KB row) ----
    {
        const int kk = lane >> 3;             // 0..7
        const int kl = (lane >> 1) & 3;       // 0..3
        const int lanepart = kk * 1024 + kl * 256 + (lane & 1) * 8;
        const int f4 = lane & 31;             // float4 index within embedding row

        #pragma unroll
        for (int p = 0; p < 16; ++p) {
            const int row = p * 4 + wv;
            const int2 ep = *reinterpret_cast<const int2*>(eidx + (size_t)(e0 + row) * 2);
            const int idx = (lane < 32) ? ep.x : ep.y;
            const float4 v = *reinterpret_cast<const float4*>(emd + (size_t)idx * D_C + f4 * 4);
            uint2 pk;
            pk.x = pk2bf(v.x, v.y);
            pk.y = pk2bf(v.z, v.w);
            const int m  = row >> 4;
            const int rr = row & 15;
            *reinterpret_cast<uint2*>(smem + (m * 8192 + lanepart + ((rr ^ kk) << 4))) = pk;
        }
    }
    __syncthreads();

    // ---- MFMA: each wave computes all 64 rows x its 64 output cols ----
    f32x4 acc[4][4];              // [m-frag][n-frag]
    #pragma unroll
    for (int m = 0; m < 4; ++m)
        #pragma unroll
        for (int n4 = 0; n4 < 4; ++n4) acc[m][n4] = (f32x4){0.f, 0.f, 0.f, 0.f};

    #pragma unroll
    for (int kk = 0; kk < 8; ++kk) {
        const int alow = ((lane & 48) | ((lane & 15) ^ kk)) << 4;   // swizzled slot*16
        short8 a[4];
        #pragma unroll
        for (int m = 0; m < 4; ++m)
            a[m] = *reinterpret_cast<const short8*>(smem + (m * 8 + kk) * 1024 + alow);
        #pragma unroll
        for (int n4 = 0; n4 < 4; ++n4) {
            short8 b = *reinterpret_cast<const short8*>(
                w1f + ((size_t)((wv * 4 + n4) * 8 + kk) * 64 + lane) * 8);
            #pragma unroll
            for (int m = 0; m < 4; ++m)
                acc[m][n4] = __builtin_amdgcn_mfma_f32_16x16x32_bf16(a[m], b, acc[m][n4], 0, 0, 0);
        }
    }

    // ---- fused epilogue: relu(acc + b1) * W2 -> per-lane partial logits ----
    float pr[4][4];
    #pragma unroll
    for (int m = 0; m < 4; ++m)
        #pragma unroll
        for (int g = 0; g < 4; ++g) pr[m][g] = 0.f;

    #pragma unroll
    for (int n4 = 0; n4 < 4; ++n4) {
        int n = wv * 64 + n4 * 16 + rr_c;    // C/D col = lane&15
        float b1v = b1[n];
        float w2v = W2[n];
        #pragma unroll
        for (int m = 0; m < 4; ++m)
            #pragma unroll
            for (int g = 0; g < 4; ++g) {
                float h = acc[m][n4][g] + b1v;
                h = h > 0.f ? h : 0.f;
                pr[m][g] += h * w2v;
            }
    }

    // reduce over the 16 cols held across rr_c lanes
    #pragma unroll
    for (int msk = 8; msk >= 1; msk >>= 1) {
        #pragma unroll
        for (int m = 0; m < 4; ++m)
            #pragma unroll
            for (int g = 0; g < 4; ++g)
                pr[m][g] += __shfl_xor(pr[m][g], msk, 64);
    }

    __syncthreads();                 // A-tile reads done; safe to reuse smem
    float* partial = (float*)smem;   // [4 waves][64 rows]

    if (rr_c == 0) {
        #pragma unroll
        for (int m = 0; m < 4; ++m)
            #pragma unroll
            for (int g = 0; g < 4; ++g)
                partial[wv * 64 + m * 16 + lg * 4 + g] = pr[m][g];
    }
    __syncthreads();

    // final cross-wave sum + sigmoid
    if (t < 64) {
        float s = partial[t] + partial[64 + t] + partial[128 + t] + partial[192 + t] + b2[0];
        out[e0 + t] = 1.0f / (1.0f + __expf(-s));
    }
}

extern "C" void kernel_launch(void* const* d_in, const int* in_sizes, int n_in,
                              void* d_out, int out_size, void* d_ws, size_t ws_size,
                              hipStream_t stream) {
    const float* emd  = (const float*)d_in[0];
    const int*   eidx = (const int*)d_in[1];
    const float* W1   = (const float*)d_in[2];
    const float* b1   = (const float*)d_in[3];
    const float* W2   = (const float*)d_in[4];
    const float* b2   = (const float*)d_in[5];
    float* out = (float*)d_out;
    unsigned short* w1f = (unsigned short*)d_ws;   // 256*256 bf16 = 128KB, fragment-ordered

    prep_w1f<<<256, 256, 0, stream>>>(W1, w1f);

    const int nblocks = N_EDGES_C / 64;            // 9375, exact
    edge_mlp<<<nblocks, 256, 0, stream>>>(emd, eidx, w1f, b1, W2, b2, out);
}